// Round 10
// baseline (471.863 us; speedup 1.0000x reference)
//
#include <hip/hip_runtime.h>
#include <hip/hip_bf16.h>

// GLA forward, B=4 L=2048 D=1024 H=16 DK=DV=64.
// Round 10: QFV GEMM -> single-buffer 2-barrier loop at 48 KiB LDS so THREE
// blocks co-reside per CU (grid 768 = 3/CU exact): cross-block TLP hides the
// stage/drain stalls (m97/m114 mechanism; r8 ring + r9 phase-split at
// 1 block/CU were null/regression). Out-GEMM keeps r8's 3-buffer ring.

typedef __attribute__((ext_vector_type(8))) short s16x8;
typedef __attribute__((ext_vector_type(4))) float f32x4;

#define WIN 5
static const size_t NE = (size_t)8192 * 1024;

__device__ inline void gload16(const void* g, void* lds) {
  __builtin_amdgcn_global_load_lds(
      (const __attribute__((address_space(1))) unsigned int*)g,
      (__attribute__((address_space(3))) unsigned int*)lds, 16, 0, 0);
}

// ---------- QFV: 256x128, BK=64, 8 waves (4M x 2N), SINGLE buffer ----------
// 48 KiB LDS -> 3 blocks/CU. stage -> sync -> compute -> sync.
// Swizzle (verified r6-r9, bank-conflict == 0): physical byte-in-row =
// logical ^ ((row&7)<<4); inverse applied on global SRC, forward on ds_read.
__global__ __launch_bounds__(512, 6) void gemm_sb(
    const __hip_bfloat16* __restrict__ A, const __hip_bfloat16* __restrict__ Bt,
    __hip_bfloat16* __restrict__ Obf, int K) {
  __shared__ __hip_bfloat16 sa[256 * 64];  // 32 KiB
  __shared__ __hip_bfloat16 sb[128 * 64];  // 16 KiB
  const int tid = threadIdx.x;
  const int lane = tid & 63;
  const int w = tid >> 6;
  const int wm = w >> 1, wn = w & 1;
  const int bm = blockIdx.y * 256, bn = blockIdx.x * 128;

  const int srow = tid >> 3;                      // staging row within 64-row round
  const int scol = ((tid & 7) ^ (srow & 7)) * 8;  // pre-swizzled global col
  const int r15 = lane & 15, g = lane >> 4;
  const int rx = (r15 & 7) << 4;                  // read-side XOR (bytes)

  f32x4 acc[4][4] = {};
  const int NT = K / 64;
  for (int t = 0; t < NT; ++t) {
    const int bk = t * 64;
#pragma unroll
    for (int r = 0; r < 4; ++r)
      gload16(A + (size_t)(bm + r * 64 + srow) * K + bk + scol,
              &sa[r * 4096 + tid * 8]);
#pragma unroll
    for (int r = 0; r < 2; ++r)
      gload16(Bt + (size_t)(bn + r * 64 + srow) * K + bk + scol,
              &sb[r * 4096 + tid * 8]);
    __syncthreads();  // drains vmcnt(0): tile resident
    s16x8 bfr[4][2], af[4][2];
#pragma unroll
    for (int n = 0; n < 4; ++n)
#pragma unroll
      for (int ks = 0; ks < 2; ++ks)
        bfr[n][ks] = *(const s16x8*)((const char*)sb + (wn * 64 + n * 16 + r15) * 128 +
                                     ((g * 16 + ks * 64) ^ rx));
#pragma unroll
    for (int m = 0; m < 4; ++m)
#pragma unroll
      for (int ks = 0; ks < 2; ++ks)
        af[m][ks] = *(const s16x8*)((const char*)sa + (wm * 64 + m * 16 + r15) * 128 +
                                    ((g * 16 + ks * 64) ^ rx));
#pragma unroll
    for (int m = 0; m < 4; ++m)
#pragma unroll
      for (int n = 0; n < 4; ++n)
#pragma unroll
        for (int ks = 0; ks < 2; ++ks)
          acc[m][n] = __builtin_amdgcn_mfma_f32_16x16x32_bf16(
              af[m][ks], bfr[n][ks], acc[m][n], 0, 0, 0);
    __syncthreads();  // protect LDS before next stage
  }

  // epilogue: bf16 interleaved [row][3072]. C/D: col=lane&15, row=(lane>>4)*4+reg
  const int rbase = bm + wm * 64 + (lane >> 4) * 4;
#pragma unroll
  for (int m = 0; m < 4; ++m)
#pragma unroll
    for (int n = 0; n < 4; ++n) {
      const int col = bn + wn * 64 + n * 16 + r15;
#pragma unroll
      for (int r = 0; r < 4; ++r)
        Obf[(size_t)(rbase + m * 16 + r) * 3072 + col] = __float2bfloat16(acc[m][n][r]);
    }
}

// ---------- out projection: r8's 3-buffer ring (verbatim), f32 C ----------
__global__ __launch_bounds__(512, 2) void gemm_pipe(
    const __hip_bfloat16* __restrict__ A, const __hip_bfloat16* __restrict__ Bt,
    float* __restrict__ C, int K) {
  __shared__ __hip_bfloat16 sa[3][256 * 64];
  __shared__ __hip_bfloat16 sb[3][128 * 64];
  const int tid = threadIdx.x;
  const int lane = tid & 63;
  const int w = tid >> 6;
  const int wm = w >> 1, wn = w & 1;
  const int bm = blockIdx.y * 256, bn = blockIdx.x * 128;
  const int srow = tid >> 3;
  const int scol = ((tid & 7) ^ (srow & 7)) * 8;
  const int r15 = lane & 15, g = lane >> 4;
  const int rx = (r15 & 7) << 4;

  const int NT = K / 64;
#pragma unroll
  for (int t0 = 0; t0 < 2; ++t0) {
#pragma unroll
    for (int r = 0; r < 4; ++r)
      gload16(A + (size_t)(bm + r * 64 + srow) * K + t0 * 64 + scol,
              &sa[t0][r * 4096 + tid * 8]);
#pragma unroll
    for (int r = 0; r < 2; ++r)
      gload16(Bt + (size_t)(bn + r * 64 + srow) * K + t0 * 64 + scol,
              &sb[t0][r * 4096 + tid * 8]);
  }
  asm volatile("s_waitcnt vmcnt(6)" ::: "memory");
  __builtin_amdgcn_s_barrier();
  __builtin_amdgcn_sched_barrier(0);

  __hip_bfloat16 *a_cur = sa[0], *a_nxt = sa[1], *a_st = sa[2];
  __hip_bfloat16 *b_cur = sb[0], *b_nxt = sb[1], *b_st = sb[2];

  f32x4 acc[4][4] = {};
  for (int t = 0; t < NT; ++t) {
    const int bk2 = (t + 2) * 64;
    s16x8 bfr[4][2];
#pragma unroll
    for (int n = 0; n < 4; ++n)
#pragma unroll
      for (int ks = 0; ks < 2; ++ks)
        bfr[n][ks] = *(const s16x8*)((const char*)b_cur + (wn * 64 + n * 16 + r15) * 128 +
                                     ((g * 16 + ks * 64) ^ rx));
    if (t + 2 < NT) {
#pragma unroll
      for (int r = 0; r < 4; ++r)
        gload16(A + (size_t)(bm + r * 64 + srow) * K + bk2 + scol,
                a_st + r * 4096 + tid * 8);
    }
#pragma unroll
    for (int p = 0; p < 2; ++p) {
      s16x8 af[2][2];
#pragma unroll
      for (int mm = 0; mm < 2; ++mm)
#pragma unroll
        for (int ks = 0; ks < 2; ++ks)
          af[mm][ks] = *(const s16x8*)((const char*)a_cur +
                                       (wm * 64 + (p * 2 + mm) * 16 + r15) * 128 +
                                       ((g * 16 + ks * 64) ^ rx));
      if (p == 0 && t + 2 < NT) {
#pragma unroll
        for (int r = 0; r < 2; ++r)
          gload16(Bt + (size_t)(bn + r * 64 + srow) * K + bk2 + scol,
                  b_st + r * 4096 + tid * 8);
      }
      __builtin_amdgcn_s_setprio(1);
#pragma unroll
      for (int mm = 0; mm < 2; ++mm)
#pragma unroll
        for (int n = 0; n < 4; ++n)
#pragma unroll
          for (int ks = 0; ks < 2; ++ks)
            acc[p * 2 + mm][n] = __builtin_amdgcn_mfma_f32_16x16x32_bf16(
                af[mm][ks], bfr[n][ks], acc[p * 2 + mm][n], 0, 0, 0);
      __builtin_amdgcn_s_setprio(0);
      __builtin_amdgcn_sched_barrier(0);
    }
    if (t + 1 < NT) {
      if (t + 2 < NT)
        asm volatile("s_waitcnt vmcnt(6) lgkmcnt(0)" ::: "memory");
      else
        asm volatile("s_waitcnt vmcnt(0) lgkmcnt(0)" ::: "memory");
      __builtin_amdgcn_s_barrier();
      __builtin_amdgcn_sched_barrier(0);
    }
    __hip_bfloat16* ta = a_cur; a_cur = a_nxt; a_nxt = a_st; a_st = ta;
    __hip_bfloat16* tb = b_cur; b_cur = b_nxt; b_nxt = b_st; b_st = tb;
  }

  const int rbase = bm + wm * 64 + (lane >> 4) * 4;
#pragma unroll
  for (int m = 0; m < 4; ++m)
#pragma unroll
    for (int n = 0; n < 4; ++n) {
      const int col = bn + wn * 64 + n * 16 + r15;
#pragma unroll
      for (int r = 0; r < 4; ++r)
        C[(size_t)(rbase + m * 16 + r) * 1024 + col] = acc[m][n][r];
    }
}

__global__ __launch_bounds__(256) void cvt_bf16(const float* __restrict__ in,
                                                __hip_bfloat16* __restrict__ out) {
  const size_t i = ((size_t)blockIdx.x * 256 + threadIdx.x) * 4;
  float4 v = *reinterpret_cast<const float4*>(in + i);
  __hip_bfloat16 o4[4] = {__float2bfloat16(v.x), __float2bfloat16(v.y),
                          __float2bfloat16(v.z), __float2bfloat16(v.w)};
  *reinterpret_cast<uint2*>(out + i) = *reinterpret_cast<uint2*>(o4);
}

// Wt[z][n][k] = bf16(W_z[k][n]); z = blockIdx.z selects Wq/Wf/Wi/Wo.
__global__ __launch_bounds__(256) void cvt_transpose4(const float* __restrict__ Wq,
                                                      const float* __restrict__ Wf,
                                                      const float* __restrict__ Wi,
                                                      const float* __restrict__ Wo,
                                                      __hip_bfloat16* __restrict__ Wall) {
  const int z = blockIdx.z;
  const float* W = z == 0 ? Wq : z == 1 ? Wf : z == 2 ? Wi : Wo;
  __hip_bfloat16* Wt = Wall + (size_t)z * 1024 * 1024;
  __shared__ __hip_bfloat16 t[32][33];
  const int bx = blockIdx.x * 32, by = blockIdx.y * 32;
  const int tx = threadIdx.x & 31, ty = threadIdx.x >> 5;
#pragma unroll
  for (int i = 0; i < 4; ++i)
    t[ty + 8 * i][tx] = __float2bfloat16(W[(size_t)(by + ty + 8 * i) * 1024 + bx + tx]);
  __syncthreads();
#pragma unroll
  for (int i = 0; i < 4; ++i)
    Wt[(size_t)(bx + ty + 8 * i) * 1024 + by + tx] = t[tx][ty + 8 * i];
}

// In-place bf16 row softmax over the interleaved buffer.
// r < 8192: q slice (cols 0..1023), scaled by 0.125. r >= 8192: f slice
// (cols 1024..2047) -> e = softmax(f).
__global__ __launch_bounds__(256) void rowsoft2(__hip_bfloat16* __restrict__ qfv) {
  const int r = blockIdx.x;
  const int isF = r >> 13;
  const int row = r & 8191;
  __hip_bfloat16* p = qfv + (size_t)row * 3072 + (isF << 10);
  const int tid = threadIdx.x;
  ushort4 u = reinterpret_cast<ushort4*>(p)[tid];
  float4 v = make_float4(__uint_as_float((unsigned)u.x << 16),
                         __uint_as_float((unsigned)u.y << 16),
                         __uint_as_float((unsigned)u.z << 16),
                         __uint_as_float((unsigned)u.w << 16));
  float m = fmaxf(fmaxf(v.x, v.y), fmaxf(v.z, v.w));
#pragma unroll
  for (int off = 32; off; off >>= 1) m = fmaxf(m, __shfl_xor(m, off));
  __shared__ float redm[4];
  __shared__ float reds[4];
  if ((tid & 63) == 0) redm[tid >> 6] = m;
  __syncthreads();
  m = fmaxf(fmaxf(redm[0], redm[1]), fmaxf(redm[2], redm[3]));
  float e0 = expf(v.x - m), e1 = expf(v.y - m), e2 = expf(v.z - m), e3 = expf(v.w - m);
  float s = e0 + e1 + e2 + e3;
#pragma unroll
  for (int off = 32; off; off >>= 1) s += __shfl_xor(s, off);
  if ((tid & 63) == 0) reds[tid >> 6] = s;
  __syncthreads();
  s = reds[0] + reds[1] + reds[2] + reds[3];
  const float inv = (isF ? 1.0f : 0.125f) / s;
  __hip_bfloat16 o4[4] = {__float2bfloat16(e0 * inv), __float2bfloat16(e1 * inv),
                          __float2bfloat16(e2 * inv), __float2bfloat16(e3 * inv)};
  reinterpret_cast<ushort4*>(p)[tid] = *reinterpret_cast<ushort4*>(o4);
}

__device__ inline float wave_sum64(float x) {
  x += __int_as_float(__builtin_amdgcn_update_dpp(0, __float_as_int(x), 0xB1, 0xf, 0xf, true));
  x += __int_as_float(__builtin_amdgcn_update_dpp(0, __float_as_int(x), 0x4E, 0xf, 0xf, true));
  x += __int_as_float(__builtin_amdgcn_update_dpp(0, __float_as_int(x), 0x141, 0xf, 0xf, true));
  x += __int_as_float(__builtin_amdgcn_update_dpp(0, __float_as_int(x), 0x140, 0xf, 0xf, true));
  x += __int_as_float(__builtin_amdgcn_update_dpp(0, __float_as_int(x), 0x142, 0xa, 0xf, false));
  x += __int_as_float(__builtin_amdgcn_update_dpp(0, __float_as_int(x), 0x143, 0xc, 0xf, false));
  return __int_as_float(__builtin_amdgcn_readlane(__float_as_int(x), 63));
}

// Windowed GLA recurrence over bf16 interleaved [row][ q(1024) e(1024) v(1024) ].
// q pre-scaled by 0.125. One wave per (b,t,h).
__global__ __launch_bounds__(256) void gla_recur(const __hip_bfloat16* __restrict__ qfv,
                                                 __hip_bfloat16* __restrict__ o) {
  const int w = blockIdx.x * 4 + (threadIdx.x >> 6);
  const int lane = threadIdx.x & 63;
  const int h = w & 15;
  const int t = (w >> 4) & 2047;
  const int bL = w >> 15;
  const int row = (bL << 11) + t;
  const int col = (h << 6) + lane;
  const size_t rb = (size_t)row * 3072 + col;
  const float qv = __bfloat162float(qfv[rb]);
  const __hip_bfloat16* Ep = qfv + rb + 1024;
  const __hip_bfloat16* Vp = qfv + rb + 2048;
  float acc = 0.0f;
  if (t >= WIN) {
    float e[WIN + 1], pr[WIN + 1], vv[WIN + 1];
#pragma unroll
    for (int j = 0; j <= WIN; ++j) {
      e[j] = __bfloat162float(Ep[-j * 3072]);
      vv[j] = __bfloat162float(Vp[-j * 3072]);
    }
    float d = 1.0f;
#pragma unroll
    for (int j = 0; j <= WIN; ++j) {
      pr[j] = qv * d * (1.0f - e[j]);
      d *= e[j];
    }
#pragma unroll
    for (int j = 0; j <= WIN; ++j) pr[j] = wave_sum64(pr[j]);
#pragma unroll
    for (int j = 0; j <= WIN; ++j) acc = fmaf(pr[j], vv[j], acc);
  } else {
    float d = 1.0f;
    for (int j = 0; j <= t; ++j) {
      const float e = __bfloat162float(Ep[-j * 3072]);
      float pr = wave_sum64(qv * d * (1.0f - e));
      acc = fmaf(pr, __bfloat162float(Vp[-j * 3072]), acc);
      d *= e;
    }
  }
  o[(size_t)row * 1024 + col] = __float2bfloat16(acc);
}

extern "C" void kernel_launch(void* const* d_in, const int* in_sizes, int n_in,
                              void* d_out, int out_size, void* d_ws, size_t ws_size,
                              hipStream_t stream) {
  const float* X  = (const float*)d_in[0];
  const float* Wq = (const float*)d_in[1];
  const float* Wf = (const float*)d_in[2];
  const float* Wi = (const float*)d_in[3];
  const float* Wo = (const float*)d_in[4];
  float* out = (float*)d_out;

  __hip_bfloat16* qfv = (__hip_bfloat16*)d_ws;       // [8192][3072] bf16, 48 MiB
  __hip_bfloat16* Xb  = qfv + (size_t)8192 * 3072;   // 16 MiB
  __hip_bfloat16* Wall = Xb + NE;                    // [4][1024][1024] bf16, 8 MiB
  __hip_bfloat16* ob  = Xb;  // alias: Xb dead after QFV GEMM

  cvt_bf16<<<NE / 4 / 256, 256, 0, stream>>>(X, Xb);
  cvt_transpose4<<<dim3(32, 32, 4), 256, 0, stream>>>(Wq, Wf, Wi, Wo, Wall);

  gemm_sb<<<dim3(24, 32), 512, 0, stream>>>(Xb, Wall, qfv, 1024);
  rowsoft2<<<16384, 256, 0, stream>>>(qfv);
  gla_recur<<<32768, 256, 0, stream>>>(qfv, ob);
  gemm_pipe<<<dim3(8, 32), 512, 0, stream>>>(ob, Wall + (size_t)3 * 1024 * 1024,
                                             out, 1024);
}

// Round 11
// 152.262 us; speedup vs baseline: 3.0990x; 3.0990x over previous
//
#include <hip/hip_runtime.h>
#include <hip/hip_bf16.h>

// GLA forward, B=4 L=2048 D=1024 H=16 DK=DV=64.
// Round 11: r10 with ONE fix — gemm_sb launch_bounds (512,6) -> (512,2).
// r10's "6 waves/EU" floor capped the allocator at 40 VGPRs and spilled the
// 64-VGPR accumulator to scratch (FETCH 669MB, WRITE 1.1GB, 391us). With
// (512,2): VGPR ~88, LDS 48KiB -> 2 blocks/CU co-resident (16 waves/CU),
// cross-block TLP hides the single-buffer stage/drain (m97/m114 mechanism).

typedef __attribute__((ext_vector_type(8))) short s16x8;
typedef __attribute__((ext_vector_type(4))) float f32x4;

#define WIN 5
static const size_t NE = (size_t)8192 * 1024;

__device__ inline void gload16(const void* g, void* lds) {
  __builtin_amdgcn_global_load_lds(
      (const __attribute__((address_space(1))) unsigned int*)g,
      (__attribute__((address_space(3))) unsigned int*)lds, 16, 0, 0);
}

// ---------- QFV: 256x128, BK=64, 8 waves (4M x 2N), SINGLE buffer ----------
// 48 KiB LDS + ~88 VGPR -> 2 blocks/CU. stage -> sync -> compute -> sync.
// Swizzle (verified r6-r10, bank-conflict == 0): physical byte-in-row =
// logical ^ ((row&7)<<4); inverse applied on global SRC, forward on ds_read.
__global__ __launch_bounds__(512, 2) void gemm_sb(
    const __hip_bfloat16* __restrict__ A, const __hip_bfloat16* __restrict__ Bt,
    __hip_bfloat16* __restrict__ Obf, int K) {
  __shared__ __hip_bfloat16 sa[256 * 64];  // 32 KiB
  __shared__ __hip_bfloat16 sb[128 * 64];  // 16 KiB
  const int tid = threadIdx.x;
  const int lane = tid & 63;
  const int w = tid >> 6;
  const int wm = w >> 1, wn = w & 1;
  const int bm = blockIdx.y * 256, bn = blockIdx.x * 128;

  const int srow = tid >> 3;                      // staging row within 64-row round
  const int scol = ((tid & 7) ^ (srow & 7)) * 8;  // pre-swizzled global col
  const int r15 = lane & 15, g = lane >> 4;
  const int rx = (r15 & 7) << 4;                  // read-side XOR (bytes)

  f32x4 acc[4][4] = {};
  const int NT = K / 64;
  for (int t = 0; t < NT; ++t) {
    const int bk = t * 64;
#pragma unroll
    for (int r = 0; r < 4; ++r)
      gload16(A + (size_t)(bm + r * 64 + srow) * K + bk + scol,
              &sa[r * 4096 + tid * 8]);
#pragma unroll
    for (int r = 0; r < 2; ++r)
      gload16(Bt + (size_t)(bn + r * 64 + srow) * K + bk + scol,
              &sb[r * 4096 + tid * 8]);
    __syncthreads();  // drains vmcnt(0): tile resident
    s16x8 bfr[4][2], af[4][2];
#pragma unroll
    for (int n = 0; n < 4; ++n)
#pragma unroll
      for (int ks = 0; ks < 2; ++ks)
        bfr[n][ks] = *(const s16x8*)((const char*)sb + (wn * 64 + n * 16 + r15) * 128 +
                                     ((g * 16 + ks * 64) ^ rx));
#pragma unroll
    for (int m = 0; m < 4; ++m)
#pragma unroll
      for (int ks = 0; ks < 2; ++ks)
        af[m][ks] = *(const s16x8*)((const char*)sa + (wm * 64 + m * 16 + r15) * 128 +
                                    ((g * 16 + ks * 64) ^ rx));
#pragma unroll
    for (int m = 0; m < 4; ++m)
#pragma unroll
      for (int n = 0; n < 4; ++n)
#pragma unroll
        for (int ks = 0; ks < 2; ++ks)
          acc[m][n] = __builtin_amdgcn_mfma_f32_16x16x32_bf16(
              af[m][ks], bfr[n][ks], acc[m][n], 0, 0, 0);
    __syncthreads();  // protect LDS before next stage
  }

  // epilogue: bf16 interleaved [row][3072]. C/D: col=lane&15, row=(lane>>4)*4+reg
  const int rbase = bm + wm * 64 + (lane >> 4) * 4;
#pragma unroll
  for (int m = 0; m < 4; ++m)
#pragma unroll
    for (int n = 0; n < 4; ++n) {
      const int col = bn + wn * 64 + n * 16 + r15;
#pragma unroll
      for (int r = 0; r < 4; ++r)
        Obf[(size_t)(rbase + m * 16 + r) * 3072 + col] = __float2bfloat16(acc[m][n][r]);
    }
}

// ---------- out projection: r8's 3-buffer ring (verbatim), f32 C ----------
__global__ __launch_bounds__(512, 2) void gemm_pipe(
    const __hip_bfloat16* __restrict__ A, const __hip_bfloat16* __restrict__ Bt,
    float* __restrict__ C, int K) {
  __shared__ __hip_bfloat16 sa[3][256 * 64];
  __shared__ __hip_bfloat16 sb[3][128 * 64];
  const int tid = threadIdx.x;
  const int lane = tid & 63;
  const int w = tid >> 6;
  const int wm = w >> 1, wn = w & 1;
  const int bm = blockIdx.y * 256, bn = blockIdx.x * 128;
  const int srow = tid >> 3;
  const int scol = ((tid & 7) ^ (srow & 7)) * 8;
  const int r15 = lane & 15, g = lane >> 4;
  const int rx = (r15 & 7) << 4;

  const int NT = K / 64;
#pragma unroll
  for (int t0 = 0; t0 < 2; ++t0) {
#pragma unroll
    for (int r = 0; r < 4; ++r)
      gload16(A + (size_t)(bm + r * 64 + srow) * K + t0 * 64 + scol,
              &sa[t0][r * 4096 + tid * 8]);
#pragma unroll
    for (int r = 0; r < 2; ++r)
      gload16(Bt + (size_t)(bn + r * 64 + srow) * K + t0 * 64 + scol,
              &sb[t0][r * 4096 + tid * 8]);
  }
  asm volatile("s_waitcnt vmcnt(6)" ::: "memory");
  __builtin_amdgcn_s_barrier();
  __builtin_amdgcn_sched_barrier(0);

  __hip_bfloat16 *a_cur = sa[0], *a_nxt = sa[1], *a_st = sa[2];
  __hip_bfloat16 *b_cur = sb[0], *b_nxt = sb[1], *b_st = sb[2];

  f32x4 acc[4][4] = {};
  for (int t = 0; t < NT; ++t) {
    const int bk2 = (t + 2) * 64;
    s16x8 bfr[4][2];
#pragma unroll
    for (int n = 0; n < 4; ++n)
#pragma unroll
      for (int ks = 0; ks < 2; ++ks)
        bfr[n][ks] = *(const s16x8*)((const char*)b_cur + (wn * 64 + n * 16 + r15) * 128 +
                                     ((g * 16 + ks * 64) ^ rx));
    if (t + 2 < NT) {
#pragma unroll
      for (int r = 0; r < 4; ++r)
        gload16(A + (size_t)(bm + r * 64 + srow) * K + bk2 + scol,
                a_st + r * 4096 + tid * 8);
    }
#pragma unroll
    for (int p = 0; p < 2; ++p) {
      s16x8 af[2][2];
#pragma unroll
      for (int mm = 0; mm < 2; ++mm)
#pragma unroll
        for (int ks = 0; ks < 2; ++ks)
          af[mm][ks] = *(const s16x8*)((const char*)a_cur +
                                       (wm * 64 + (p * 2 + mm) * 16 + r15) * 128 +
                                       ((g * 16 + ks * 64) ^ rx));
      if (p == 0 && t + 2 < NT) {
#pragma unroll
        for (int r = 0; r < 2; ++r)
          gload16(Bt + (size_t)(bn + r * 64 + srow) * K + bk2 + scol,
                  b_st + r * 4096 + tid * 8);
      }
      __builtin_amdgcn_s_setprio(1);
#pragma unroll
      for (int mm = 0; mm < 2; ++mm)
#pragma unroll
        for (int n = 0; n < 4; ++n)
#pragma unroll
          for (int ks = 0; ks < 2; ++ks)
            acc[p * 2 + mm][n] = __builtin_amdgcn_mfma_f32_16x16x32_bf16(
                af[mm][ks], bfr[n][ks], acc[p * 2 + mm][n], 0, 0, 0);
      __builtin_amdgcn_s_setprio(0);
      __builtin_amdgcn_sched_barrier(0);
    }
    if (t + 1 < NT) {
      if (t + 2 < NT)
        asm volatile("s_waitcnt vmcnt(6) lgkmcnt(0)" ::: "memory");
      else
        asm volatile("s_waitcnt vmcnt(0) lgkmcnt(0)" ::: "memory");
      __builtin_amdgcn_s_barrier();
      __builtin_amdgcn_sched_barrier(0);
    }
    __hip_bfloat16* ta = a_cur; a_cur = a_nxt; a_nxt = a_st; a_st = ta;
    __hip_bfloat16* tb = b_cur; b_cur = b_nxt; b_nxt = b_st; b_st = tb;
  }

  const int rbase = bm + wm * 64 + (lane >> 4) * 4;
#pragma unroll
  for (int m = 0; m < 4; ++m)
#pragma unroll
    for (int n = 0; n < 4; ++n) {
      const int col = bn + wn * 64 + n * 16 + r15;
#pragma unroll
      for (int r = 0; r < 4; ++r)
        C[(size_t)(rbase + m * 16 + r) * 1024 + col] = acc[m][n][r];
    }
}

__global__ __launch_bounds__(256) void cvt_bf16(const float* __restrict__ in,
                                                __hip_bfloat16* __restrict__ out) {
  const size_t i = ((size_t)blockIdx.x * 256 + threadIdx.x) * 4;
  float4 v = *reinterpret_cast<const float4*>(in + i);
  __hip_bfloat16 o4[4] = {__float2bfloat16(v.x), __float2bfloat16(v.y),
                          __float2bfloat16(v.z), __float2bfloat16(v.w)};
  *reinterpret_cast<uint2*>(out + i) = *reinterpret_cast<uint2*>(o4);
}

// Wt[z][n][k] = bf16(W_z[k][n]); z = blockIdx.z selects Wq/Wf/Wi/Wo.
__global__ __launch_bounds__(256) void cvt_transpose4(const float* __restrict__ Wq,
                                                      const float* __restrict__ Wf,
                                                      const float* __restrict__ Wi,
                                                      const float* __restrict__ Wo,
                                                      __hip_bfloat16* __restrict__ Wall) {
  const int z = blockIdx.z;
  const float* W = z == 0 ? Wq : z == 1 ? Wf : z == 2 ? Wi : Wo;
  __hip_bfloat16* Wt = Wall + (size_t)z * 1024 * 1024;
  __shared__ __hip_bfloat16 t[32][33];
  const int bx = blockIdx.x * 32, by = blockIdx.y * 32;
  const int tx = threadIdx.x & 31, ty = threadIdx.x >> 5;
#pragma unroll
  for (int i = 0; i < 4; ++i)
    t[ty + 8 * i][tx] = __float2bfloat16(W[(size_t)(by + ty + 8 * i) * 1024 + bx + tx]);
  __syncthreads();
#pragma unroll
  for (int i = 0; i < 4; ++i)
    Wt[(size_t)(bx + ty + 8 * i) * 1024 + by + tx] = t[tx][ty + 8 * i];
}

// In-place bf16 row softmax over the interleaved buffer.
// r < 8192: q slice (cols 0..1023), scaled by 0.125. r >= 8192: f slice
// (cols 1024..2047) -> e = softmax(f).
__global__ __launch_bounds__(256) void rowsoft2(__hip_bfloat16* __restrict__ qfv) {
  const int r = blockIdx.x;
  const int isF = r >> 13;
  const int row = r & 8191;
  __hip_bfloat16* p = qfv + (size_t)row * 3072 + (isF << 10);
  const int tid = threadIdx.x;
  ushort4 u = reinterpret_cast<ushort4*>(p)[tid];
  float4 v = make_float4(__uint_as_float((unsigned)u.x << 16),
                         __uint_as_float((unsigned)u.y << 16),
                         __uint_as_float((unsigned)u.z << 16),
                         __uint_as_float((unsigned)u.w << 16));
  float m = fmaxf(fmaxf(v.x, v.y), fmaxf(v.z, v.w));
#pragma unroll
  for (int off = 32; off; off >>= 1) m = fmaxf(m, __shfl_xor(m, off));
  __shared__ float redm[4];
  __shared__ float reds[4];
  if ((tid & 63) == 0) redm[tid >> 6] = m;
  __syncthreads();
  m = fmaxf(fmaxf(redm[0], redm[1]), fmaxf(redm[2], redm[3]));
  float e0 = expf(v.x - m), e1 = expf(v.y - m), e2 = expf(v.z - m), e3 = expf(v.w - m);
  float s = e0 + e1 + e2 + e3;
#pragma unroll
  for (int off = 32; off; off >>= 1) s += __shfl_xor(s, off);
  if ((tid & 63) == 0) reds[tid >> 6] = s;
  __syncthreads();
  s = reds[0] + reds[1] + reds[2] + reds[3];
  const float inv = (isF ? 1.0f : 0.125f) / s;
  __hip_bfloat16 o4[4] = {__float2bfloat16(e0 * inv), __float2bfloat16(e1 * inv),
                          __float2bfloat16(e2 * inv), __float2bfloat16(e3 * inv)};
  reinterpret_cast<ushort4*>(p)[tid] = *reinterpret_cast<ushort4*>(o4);
}

__device__ inline float wave_sum64(float x) {
  x += __int_as_float(__builtin_amdgcn_update_dpp(0, __float_as_int(x), 0xB1, 0xf, 0xf, true));
  x += __int_as_float(__builtin_amdgcn_update_dpp(0, __float_as_int(x), 0x4E, 0xf, 0xf, true));
  x += __int_as_float(__builtin_amdgcn_update_dpp(0, __float_as_int(x), 0x141, 0xf, 0xf, true));
  x += __int_as_float(__builtin_amdgcn_update_dpp(0, __float_as_int(x), 0x140, 0xf, 0xf, true));
  x += __int_as_float(__builtin_amdgcn_update_dpp(0, __float_as_int(x), 0x142, 0xa, 0xf, false));
  x += __int_as_float(__builtin_amdgcn_update_dpp(0, __float_as_int(x), 0x143, 0xc, 0xf, false));
  return __int_as_float(__builtin_amdgcn_readlane(__float_as_int(x), 63));
}

// Windowed GLA recurrence over bf16 interleaved [row][ q(1024) e(1024) v(1024) ].
// q pre-scaled by 0.125. One wave per (b,t,h).
__global__ __launch_bounds__(256) void gla_recur(const __hip_bfloat16* __restrict__ qfv,
                                                 __hip_bfloat16* __restrict__ o) {
  const int w = blockIdx.x * 4 + (threadIdx.x >> 6);
  const int lane = threadIdx.x & 63;
  const int h = w & 15;
  const int t = (w >> 4) & 2047;
  const int bL = w >> 15;
  const int row = (bL << 11) + t;
  const int col = (h << 6) + lane;
  const size_t rb = (size_t)row * 3072 + col;
  const float qv = __bfloat162float(qfv[rb]);
  const __hip_bfloat16* Ep = qfv + rb + 1024;
  const __hip_bfloat16* Vp = qfv + rb + 2048;
  float acc = 0.0f;
  if (t >= WIN) {
    float e[WIN + 1], pr[WIN + 1], vv[WIN + 1];
#pragma unroll
    for (int j = 0; j <= WIN; ++j) {
      e[j] = __bfloat162float(Ep[-j * 3072]);
      vv[j] = __bfloat162float(Vp[-j * 3072]);
    }
    float d = 1.0f;
#pragma unroll
    for (int j = 0; j <= WIN; ++j) {
      pr[j] = qv * d * (1.0f - e[j]);
      d *= e[j];
    }
#pragma unroll
    for (int j = 0; j <= WIN; ++j) pr[j] = wave_sum64(pr[j]);
#pragma unroll
    for (int j = 0; j <= WIN; ++j) acc = fmaf(pr[j], vv[j], acc);
  } else {
    float d = 1.0f;
    for (int j = 0; j <= t; ++j) {
      const float e = __bfloat162float(Ep[-j * 3072]);
      float pr = wave_sum64(qv * d * (1.0f - e));
      acc = fmaf(pr, __bfloat162float(Vp[-j * 3072]), acc);
      d *= e;
    }
  }
  o[(size_t)row * 1024 + col] = __float2bfloat16(acc);
}

extern "C" void kernel_launch(void* const* d_in, const int* in_sizes, int n_in,
                              void* d_out, int out_size, void* d_ws, size_t ws_size,
                              hipStream_t stream) {
  const float* X  = (const float*)d_in[0];
  const float* Wq = (const float*)d_in[1];
  const float* Wf = (const float*)d_in[2];
  const float* Wi = (const float*)d_in[3];
  const float* Wo = (const float*)d_in[4];
  float* out = (float*)d_out;

  __hip_bfloat16* qfv = (__hip_bfloat16*)d_ws;       // [8192][3072] bf16, 48 MiB
  __hip_bfloat16* Xb  = qfv + (size_t)8192 * 3072;   // 16 MiB
  __hip_bfloat16* Wall = Xb + NE;                    // [4][1024][1024] bf16, 8 MiB
  __hip_bfloat16* ob  = Xb;  // alias: Xb dead after QFV GEMM

  cvt_bf16<<<NE / 4 / 256, 256, 0, stream>>>(X, Xb);
  cvt_transpose4<<<dim3(32, 32, 4), 256, 0, stream>>>(Wq, Wf, Wi, Wo, Wall);

  gemm_sb<<<dim3(24, 32), 512, 0, stream>>>(Xb, Wall, qfv, 1024);
  rowsoft2<<<16384, 256, 0, stream>>>(qfv);
  gla_recur<<<32768, 256, 0, stream>>>(qfv, ob);
  gemm_pipe<<<dim3(8, 32), 512, 0, stream>>>(ob, Wall + (size_t)3 * 1024 * 1024,
                                             out, 1024);
}

// Round 12
// 148.566 us; speedup vs baseline: 3.1761x; 1.0249x over previous
//
#include <hip/hip_runtime.h>
#include <hip/hip_bf16.h>

// GLA forward, B=4 L=2048 D=1024 H=16 DK=DV=64.
// Round 12: out-GEMM rebuilt as the PROVEN single-buffer 2-barrier structure
// (128x128/BK=64, 32KiB LDS, grid 512 = 2 blocks/CU -> cross-block TLP, the
// mechanism that put QFV at 872 TF). rowsoft2: DPP wave reductions (no
// ds_bpermute chains) + q-row/f-row fused per block. QFV gemm_sb unchanged.

typedef __attribute__((ext_vector_type(8))) short s16x8;
typedef __attribute__((ext_vector_type(4))) float f32x4;

#define WIN 5
static const size_t NE = (size_t)8192 * 1024;

__device__ inline void gload16(const void* g, void* lds) {
  __builtin_amdgcn_global_load_lds(
      (const __attribute__((address_space(1))) unsigned int*)g,
      (__attribute__((address_space(3))) unsigned int*)lds, 16, 0, 0);
}

// ---------- QFV: 256x128, BK=64, 8 waves (4M x 2N), SINGLE buffer ----------
// (verified r11: 59.3us, 872 TF, zero bank conflicts, clean traffic)
__global__ __launch_bounds__(512, 2) void gemm_sb(
    const __hip_bfloat16* __restrict__ A, const __hip_bfloat16* __restrict__ Bt,
    __hip_bfloat16* __restrict__ Obf, int K) {
  __shared__ __hip_bfloat16 sa[256 * 64];  // 32 KiB
  __shared__ __hip_bfloat16 sb[128 * 64];  // 16 KiB
  const int tid = threadIdx.x;
  const int lane = tid & 63;
  const int w = tid >> 6;
  const int wm = w >> 1, wn = w & 1;
  const int bm = blockIdx.y * 256, bn = blockIdx.x * 128;

  const int srow = tid >> 3;                      // 0..63
  const int scol = ((tid & 7) ^ (srow & 7)) * 8;  // pre-swizzled global col
  const int r15 = lane & 15, g = lane >> 4;
  const int rx = (r15 & 7) << 4;                  // read-side XOR (bytes)

  f32x4 acc[4][4] = {};
  const int NT = K / 64;
  for (int t = 0; t < NT; ++t) {
    const int bk = t * 64;
#pragma unroll
    for (int r = 0; r < 4; ++r)
      gload16(A + (size_t)(bm + r * 64 + srow) * K + bk + scol,
              &sa[r * 4096 + tid * 8]);
#pragma unroll
    for (int r = 0; r < 2; ++r)
      gload16(Bt + (size_t)(bn + r * 64 + srow) * K + bk + scol,
              &sb[r * 4096 + tid * 8]);
    __syncthreads();
    s16x8 bfr[4][2], af[4][2];
#pragma unroll
    for (int n = 0; n < 4; ++n)
#pragma unroll
      for (int ks = 0; ks < 2; ++ks)
        bfr[n][ks] = *(const s16x8*)((const char*)sb + (wn * 64 + n * 16 + r15) * 128 +
                                     ((g * 16 + ks * 64) ^ rx));
#pragma unroll
    for (int m = 0; m < 4; ++m)
#pragma unroll
      for (int ks = 0; ks < 2; ++ks)
        af[m][ks] = *(const s16x8*)((const char*)sa + (wm * 64 + m * 16 + r15) * 128 +
                                    ((g * 16 + ks * 64) ^ rx));
#pragma unroll
    for (int m = 0; m < 4; ++m)
#pragma unroll
      for (int n = 0; n < 4; ++n)
#pragma unroll
        for (int ks = 0; ks < 2; ++ks)
          acc[m][n] = __builtin_amdgcn_mfma_f32_16x16x32_bf16(
              af[m][ks], bfr[n][ks], acc[m][n], 0, 0, 0);
    __syncthreads();
  }

  const int rbase = bm + wm * 64 + (lane >> 4) * 4;
#pragma unroll
  for (int m = 0; m < 4; ++m)
#pragma unroll
    for (int n = 0; n < 4; ++n) {
      const int col = bn + wn * 64 + n * 16 + r15;
#pragma unroll
      for (int r = 0; r < 4; ++r)
        Obf[(size_t)(rbase + m * 16 + r) * 3072 + col] = __float2bfloat16(acc[m][n][r]);
    }
}

// ---------- out projection: 128x128, BK=64, 4 waves (2x2), SINGLE buffer ----
// 32 KiB LDS, grid (8,64)=512 = 2 blocks/CU: same cross-block-TLP mechanism.
__global__ __launch_bounds__(256, 2) void gemm_sb128(
    const __hip_bfloat16* __restrict__ A, const __hip_bfloat16* __restrict__ Bt,
    float* __restrict__ C, int K) {
  __shared__ __hip_bfloat16 sa[128 * 64];  // 16 KiB
  __shared__ __hip_bfloat16 sb[128 * 64];  // 16 KiB
  const int tid = threadIdx.x;
  const int lane = tid & 63;
  const int w = tid >> 6;                  // 0..3
  const int wm = w >> 1, wn = w & 1;
  const int bm = blockIdx.y * 128, bn = blockIdx.x * 128;

  const int srow = tid >> 3;               // 0..31 per staging round
  const int scol = ((tid & 7) ^ (srow & 7)) * 8;
  const int r15 = lane & 15, g = lane >> 4;
  const int rx = (r15 & 7) << 4;

  f32x4 acc[4][4] = {};
  const int NT = K / 64;
  for (int t = 0; t < NT; ++t) {
    const int bk = t * 64;
#pragma unroll
    for (int r = 0; r < 4; ++r)
      gload16(A + (size_t)(bm + r * 32 + srow) * K + bk + scol,
              &sa[r * 2048 + tid * 8]);
#pragma unroll
    for (int r = 0; r < 4; ++r)
      gload16(Bt + (size_t)(bn + r * 32 + srow) * K + bk + scol,
              &sb[r * 2048 + tid * 8]);
    __syncthreads();
    s16x8 bfr[4][2], af[4][2];
#pragma unroll
    for (int n = 0; n < 4; ++n)
#pragma unroll
      for (int ks = 0; ks < 2; ++ks)
        bfr[n][ks] = *(const s16x8*)((const char*)sb + (wn * 64 + n * 16 + r15) * 128 +
                                     ((g * 16 + ks * 64) ^ rx));
#pragma unroll
    for (int m = 0; m < 4; ++m)
#pragma unroll
      for (int ks = 0; ks < 2; ++ks)
        af[m][ks] = *(const s16x8*)((const char*)sa + (wm * 64 + m * 16 + r15) * 128 +
                                    ((g * 16 + ks * 64) ^ rx));
#pragma unroll
    for (int m = 0; m < 4; ++m)
#pragma unroll
      for (int n = 0; n < 4; ++n)
#pragma unroll
        for (int ks = 0; ks < 2; ++ks)
          acc[m][n] = __builtin_amdgcn_mfma_f32_16x16x32_bf16(
              af[m][ks], bfr[n][ks], acc[m][n], 0, 0, 0);
    __syncthreads();
  }

  const int rbase = bm + wm * 64 + (lane >> 4) * 4;
#pragma unroll
  for (int m = 0; m < 4; ++m)
#pragma unroll
    for (int n = 0; n < 4; ++n) {
      const int col = bn + wn * 64 + n * 16 + r15;
#pragma unroll
      for (int r = 0; r < 4; ++r)
        C[(size_t)(rbase + m * 16 + r) * 1024 + col] = acc[m][n][r];
    }
}

__global__ __launch_bounds__(256) void cvt_bf16(const float* __restrict__ in,
                                                __hip_bfloat16* __restrict__ out) {
  const size_t i = ((size_t)blockIdx.x * 256 + threadIdx.x) * 4;
  float4 v = *reinterpret_cast<const float4*>(in + i);
  __hip_bfloat16 o4[4] = {__float2bfloat16(v.x), __float2bfloat16(v.y),
                          __float2bfloat16(v.z), __float2bfloat16(v.w)};
  *reinterpret_cast<uint2*>(out + i) = *reinterpret_cast<uint2*>(o4);
}

// Wt[z][n][k] = bf16(W_z[k][n]); z = blockIdx.z selects Wq/Wf/Wi/Wo.
__global__ __launch_bounds__(256) void cvt_transpose4(const float* __restrict__ Wq,
                                                      const float* __restrict__ Wf,
                                                      const float* __restrict__ Wi,
                                                      const float* __restrict__ Wo,
                                                      __hip_bfloat16* __restrict__ Wall) {
  const int z = blockIdx.z;
  const float* W = z == 0 ? Wq : z == 1 ? Wf : z == 2 ? Wi : Wo;
  __hip_bfloat16* Wt = Wall + (size_t)z * 1024 * 1024;
  __shared__ __hip_bfloat16 t[32][33];
  const int bx = blockIdx.x * 32, by = blockIdx.y * 32;
  const int tx = threadIdx.x & 31, ty = threadIdx.x >> 5;
#pragma unroll
  for (int i = 0; i < 4; ++i)
    t[ty + 8 * i][tx] = __float2bfloat16(W[(size_t)(by + ty + 8 * i) * 1024 + bx + tx]);
  __syncthreads();
#pragma unroll
  for (int i = 0; i < 4; ++i)
    Wt[(size_t)(bx + ty + 8 * i) * 1024 + by + tx] = t[tx][ty + 8 * i];
}

// ---- DPP full-wave reductions (pure VALU; no ds_bpermute). Lane 63 holds
// the result; readlane broadcasts. Verified pattern (r3+). ----
__device__ inline float wave_sum64(float x) {
  x += __int_as_float(__builtin_amdgcn_update_dpp(0, __float_as_int(x), 0xB1, 0xf, 0xf, true));
  x += __int_as_float(__builtin_amdgcn_update_dpp(0, __float_as_int(x), 0x4E, 0xf, 0xf, true));
  x += __int_as_float(__builtin_amdgcn_update_dpp(0, __float_as_int(x), 0x141, 0xf, 0xf, true));
  x += __int_as_float(__builtin_amdgcn_update_dpp(0, __float_as_int(x), 0x140, 0xf, 0xf, true));
  x += __int_as_float(__builtin_amdgcn_update_dpp(0, __float_as_int(x), 0x142, 0xa, 0xf, false));
  x += __int_as_float(__builtin_amdgcn_update_dpp(0, __float_as_int(x), 0x143, 0xc, 0xf, false));
  return __int_as_float(__builtin_amdgcn_readlane(__float_as_int(x), 63));
}
__device__ inline float wave_max64(float x) {
  x = fmaxf(x, __int_as_float(__builtin_amdgcn_update_dpp(0, __float_as_int(x), 0xB1, 0xf, 0xf, true)));
  x = fmaxf(x, __int_as_float(__builtin_amdgcn_update_dpp(0, __float_as_int(x), 0x4E, 0xf, 0xf, true)));
  x = fmaxf(x, __int_as_float(__builtin_amdgcn_update_dpp(0, __float_as_int(x), 0x141, 0xf, 0xf, true)));
  x = fmaxf(x, __int_as_float(__builtin_amdgcn_update_dpp(0, __float_as_int(x), 0x140, 0xf, 0xf, true)));
  x = fmaxf(x, __int_as_float(__builtin_amdgcn_update_dpp(0, __float_as_int(x), 0x142, 0xa, 0xf, false)));
  x = fmaxf(x, __int_as_float(__builtin_amdgcn_update_dpp(0, __float_as_int(x), 0x143, 0xc, 0xf, false)));
  return __int_as_float(__builtin_amdgcn_readlane(__float_as_int(x), 63));
}

// One block per row: q slice (softmax * 0.125) AND f slice (e = softmax(f)),
// both in place. Two independent reduction chains interleave for latency
// hiding; DPP per-wave reduce + LDS cross-wave combine.
__global__ __launch_bounds__(256) void rowsoft2(__hip_bfloat16* __restrict__ qfv) {
  const int row = blockIdx.x;
  const int tid = threadIdx.x;
  const int wv = tid >> 6;
  __hip_bfloat16* pq = qfv + (size_t)row * 3072;
  __hip_bfloat16* pf = pq + 1024;
  ushort4 uq = reinterpret_cast<ushort4*>(pq)[tid];
  ushort4 uf = reinterpret_cast<ushort4*>(pf)[tid];
  float q0 = __uint_as_float((unsigned)uq.x << 16), q1 = __uint_as_float((unsigned)uq.y << 16);
  float q2 = __uint_as_float((unsigned)uq.z << 16), q3 = __uint_as_float((unsigned)uq.w << 16);
  float f0 = __uint_as_float((unsigned)uf.x << 16), f1 = __uint_as_float((unsigned)uf.y << 16);
  float f2 = __uint_as_float((unsigned)uf.z << 16), f3 = __uint_as_float((unsigned)uf.w << 16);

  float mq = wave_max64(fmaxf(fmaxf(q0, q1), fmaxf(q2, q3)));
  float mf = wave_max64(fmaxf(fmaxf(f0, f1), fmaxf(f2, f3)));
  __shared__ float red[4][8];
  if ((tid & 63) == 0) { red[wv][0] = mq; red[wv][1] = mf; }
  __syncthreads();
  mq = fmaxf(fmaxf(red[0][0], red[1][0]), fmaxf(red[2][0], red[3][0]));
  mf = fmaxf(fmaxf(red[0][1], red[1][1]), fmaxf(red[2][1], red[3][1]));

  float eq0 = expf(q0 - mq), eq1 = expf(q1 - mq), eq2 = expf(q2 - mq), eq3 = expf(q3 - mq);
  float ef0 = expf(f0 - mf), ef1 = expf(f1 - mf), ef2 = expf(f2 - mf), ef3 = expf(f3 - mf);
  float sq = wave_sum64(eq0 + eq1 + eq2 + eq3);
  float sf = wave_sum64(ef0 + ef1 + ef2 + ef3);
  if ((tid & 63) == 0) { red[wv][2] = sq; red[wv][3] = sf; }
  __syncthreads();
  sq = red[0][2] + red[1][2] + red[2][2] + red[3][2];
  sf = red[0][3] + red[1][3] + red[2][3] + red[3][3];

  const float iq = 0.125f / sq, iff = 1.0f / sf;
  __hip_bfloat16 oq[4] = {__float2bfloat16(eq0 * iq), __float2bfloat16(eq1 * iq),
                          __float2bfloat16(eq2 * iq), __float2bfloat16(eq3 * iq)};
  __hip_bfloat16 of[4] = {__float2bfloat16(ef0 * iff), __float2bfloat16(ef1 * iff),
                          __float2bfloat16(ef2 * iff), __float2bfloat16(ef3 * iff)};
  reinterpret_cast<ushort4*>(pq)[tid] = *reinterpret_cast<ushort4*>(oq);
  reinterpret_cast<ushort4*>(pf)[tid] = *reinterpret_cast<ushort4*>(of);
}

// Windowed GLA recurrence over bf16 interleaved [row][ q(1024) e(1024) v(1024) ].
// q pre-scaled by 0.125. One wave per (b,t,h).
__global__ __launch_bounds__(256) void gla_recur(const __hip_bfloat16* __restrict__ qfv,
                                                 __hip_bfloat16* __restrict__ o) {
  const int w = blockIdx.x * 4 + (threadIdx.x >> 6);
  const int lane = threadIdx.x & 63;
  const int h = w & 15;
  const int t = (w >> 4) & 2047;
  const int bL = w >> 15;
  const int row = (bL << 11) + t;
  const int col = (h << 6) + lane;
  const size_t rb = (size_t)row * 3072 + col;
  const float qv = __bfloat162float(qfv[rb]);
  const __hip_bfloat16* Ep = qfv + rb + 1024;
  const __hip_bfloat16* Vp = qfv + rb + 2048;
  float acc = 0.0f;
  if (t >= WIN) {
    float e[WIN + 1], pr[WIN + 1], vv[WIN + 1];
#pragma unroll
    for (int j = 0; j <= WIN; ++j) {
      e[j] = __bfloat162float(Ep[-j * 3072]);
      vv[j] = __bfloat162float(Vp[-j * 3072]);
    }
    float d = 1.0f;
#pragma unroll
    for (int j = 0; j <= WIN; ++j) {
      pr[j] = qv * d * (1.0f - e[j]);
      d *= e[j];
    }
#pragma unroll
    for (int j = 0; j <= WIN; ++j) pr[j] = wave_sum64(pr[j]);
#pragma unroll
    for (int j = 0; j <= WIN; ++j) acc = fmaf(pr[j], vv[j], acc);
  } else {
    float d = 1.0f;
    for (int j = 0; j <= t; ++j) {
      const float e = __bfloat162float(Ep[-j * 3072]);
      float pr = wave_sum64(qv * d * (1.0f - e));
      acc = fmaf(pr, __bfloat162float(Vp[-j * 3072]), acc);
      d *= e;
    }
  }
  o[(size_t)row * 1024 + col] = __float2bfloat16(acc);
}

extern "C" void kernel_launch(void* const* d_in, const int* in_sizes, int n_in,
                              void* d_out, int out_size, void* d_ws, size_t ws_size,
                              hipStream_t stream) {
  const float* X  = (const float*)d_in[0];
  const float* Wq = (const float*)d_in[1];
  const float* Wf = (const float*)d_in[2];
  const float* Wi = (const float*)d_in[3];
  const float* Wo = (const float*)d_in[4];
  float* out = (float*)d_out;

  __hip_bfloat16* qfv = (__hip_bfloat16*)d_ws;       // [8192][3072] bf16, 48 MiB
  __hip_bfloat16* Xb  = qfv + (size_t)8192 * 3072;   // 16 MiB
  __hip_bfloat16* Wall = Xb + NE;                    // [4][1024][1024] bf16, 8 MiB
  __hip_bfloat16* ob  = Xb;  // alias: Xb dead after QFV GEMM

  cvt_bf16<<<NE / 4 / 256, 256, 0, stream>>>(X, Xb);
  cvt_transpose4<<<dim3(32, 32, 4), 256, 0, stream>>>(Wq, Wf, Wi, Wo, Wall);

  gemm_sb<<<dim3(24, 32), 512, 0, stream>>>(Xb, Wall, qfv, 1024);
  rowsoft2<<<8192, 256, 0, stream>>>(qfv);
  gla_recur<<<32768, 256, 0, stream>>>(qfv, ob);
  gemm_sb128<<<dim3(8, 64), 256, 0, stream>>>(ob, Wall + (size_t)3 * 1024 * 1024,
                                              out, 1024);
}